// Round 1
// baseline (34.754 us; speedup 1.0000x reference)
//
#include <hip/hip_runtime.h>

#define TILE 256
#define ALPHA 0.7f
#define MARGIN 0.5f

// Pairwise ranking-hinge + MSE partial reduction.
// Tile (ti, tj) covers i in [ti*256, ...), j in [tj*256, ...). Only tj >= ti
// tiles run; off-diagonal tiles need no i<j check (i_max < j_min).
__global__ __launch_bounds__(256) void pair_kernel(const float* __restrict__ p,
                                                   const float* __restrict__ t,
                                                   int B, double* __restrict__ ws) {
    const int ti = blockIdx.y;
    const int tj = blockIdx.x;
    if (tj < ti) return;

    __shared__ float s_t[TILE];
    __shared__ float s_p[TILE];

    const int tid = threadIdx.x;
    const int ig0 = ti * TILE;
    const int jg  = tj * TILE + tid;

    // stage i-tile into LDS
    {
        const int ig = ig0 + tid;
        const bool iv = ig < B;
        s_t[tid] = iv ? t[ig] : 0.0f;
        s_p[tid] = iv ? p[ig] : 0.0f;
    }
    __syncthreads();

    const bool jvalid = jg < B;
    const float tjv = jvalid ? t[jg] : 0.0f;
    const float pjv = jvalid ? p[jg] : 0.0f;

    float sum  = 0.0f;   // ranking hinge partial
    int   cnt  = 0;      // valid-pair count partial
    float msev = 0.0f;   // mse partial (diagonal tiles only)

    const int ilim = min(TILE, B - ig0);

    if (ti == tj) {
        if (jvalid) {
            const float d = pjv - tjv;
            msev = d * d;
            const int imax = min(ilim, tid);  // i (tile-local) < tid  ->  global i < j
            for (int ii = 0; ii < imax; ++ii) {
                const float dt = s_t[ii] - tjv;
                const float dp = s_p[ii] - pjv;
                const float sdp = (dt > 0.0f) ? dp : -dp;
                const float v = fmaxf(MARGIN - sdp, 0.0f);
                const bool valid = (dt != 0.0f);
                sum += valid ? v : 0.0f;
                cnt += valid ? 1 : 0;
            }
        }
    } else {
        if (jvalid) {
            #pragma unroll 4
            for (int ii = 0; ii < ilim; ++ii) {
                const float dt = s_t[ii] - tjv;
                const float dp = s_p[ii] - pjv;
                const float sdp = (dt > 0.0f) ? dp : -dp;
                const float v = fmaxf(MARGIN - sdp, 0.0f);
                const bool valid = (dt != 0.0f);
                sum += valid ? v : 0.0f;
                cnt += valid ? 1 : 0;
            }
        }
    }

    // wave (64-lane) butterfly reduction
    float csum = (float)0;  // keep cnt exact in int until cross-wave stage
    (void)csum;
    for (int off = 32; off > 0; off >>= 1) {
        sum  += __shfl_down(sum, off);
        cnt  += __shfl_down(cnt, off);
        msev += __shfl_down(msev, off);
    }

    __shared__ double r_sum[4];
    __shared__ double r_mse[4];
    __shared__ int    r_cnt[4];
    const int wid  = tid >> 6;
    const int lane = tid & 63;
    if (lane == 0) {
        r_sum[wid] = (double)sum;
        r_mse[wid] = (double)msev;
        r_cnt[wid] = cnt;
    }
    __syncthreads();
    if (tid == 0) {
        const double S = r_sum[0] + r_sum[1] + r_sum[2] + r_sum[3];
        const double M = r_mse[0] + r_mse[1] + r_mse[2] + r_mse[3];
        const long long C = (long long)r_cnt[0] + r_cnt[1] + r_cnt[2] + r_cnt[3];
        if (S != 0.0) atomicAdd(&ws[0], S);
        if (C != 0)   atomicAdd(&ws[1], (double)C);
        if (M != 0.0) atomicAdd(&ws[2], M);
    }
}

__global__ void finalize_kernel(const double* __restrict__ ws,
                                float* __restrict__ out, int B) {
    const double S = ws[0];
    const double C = ws[1];
    const double M = ws[2];
    const double mse = M / (double)B;
    const double rank = (C > 0.0) ? (S / fmax(C, 1.0)) : 0.0;
    out[0] = (float)((double)ALPHA * mse + (double)(1.0f - ALPHA) * rank);
}

extern "C" void kernel_launch(void* const* d_in, const int* in_sizes, int n_in,
                              void* d_out, int out_size, void* d_ws, size_t ws_size,
                              hipStream_t stream) {
    const float* p = (const float*)d_in[0];
    const float* t = (const float*)d_in[1];
    const int B = in_sizes[0];

    double* ws = (double*)d_ws;
    hipMemsetAsync(d_ws, 0, 3 * sizeof(double), stream);

    const int nt = (B + TILE - 1) / TILE;
    dim3 grid(nt, nt);
    pair_kernel<<<grid, dim3(TILE), 0, stream>>>(p, t, B, ws);
    finalize_kernel<<<1, 1, 0, stream>>>(ws, (float*)d_out, B);
}

// Round 2
// 19.853 us; speedup vs baseline: 1.7506x; 1.7506x over previous
//
#include <hip/hip_runtime.h>

#define ALPHA 0.7f
#define MARGIN 0.5f
#define TI 128   // i-tile height (staged in LDS)
#define TJ 256   // j-tile width (= threads per block, 1 j per thread)

// Tile decomposition: j-tiles of 256 (one per 256-thread block column),
// i-tiles of 128. For j-tile jt, i-tiles it = 0 .. 2*jt+1 are launched:
//   it <  2*jt      -> full tile (every i < every j, no predicate)
//   it in {2jt,2jt+1} -> partial tile (per-pair i<j predicate)
// Linear block id -> (jt, it): column jt starts at K(jt) = jt*(jt+1).
// Total blocks NB = NJ*(NJ+1), NJ = ceil(B/TJ).  (B=8192 -> 1056 blocks)
__global__ __launch_bounds__(256) void pair_kernel(const float* __restrict__ p,
                                                   const float* __restrict__ t,
                                                   int B,
                                                   float* __restrict__ bsum,
                                                   float* __restrict__ bmse,
                                                   int*   __restrict__ bcnt) {
    const int bid = blockIdx.x;
    // jt = largest jt with jt*(jt+1) <= bid
    int jt = (int)((sqrtf(4.0f * (float)bid + 1.0f) - 1.0f) * 0.5f);
    while ((jt + 1) * (jt + 2) <= bid) ++jt;
    while (jt * (jt + 1) > bid) --jt;
    const int it = bid - jt * (jt + 1);

    const int tid = threadIdx.x;
    const int ig0 = it * TI;
    const int jg  = jt * TJ + tid;

    __shared__ float s_t[TI];
    __shared__ float s_p[TI];
    if (tid < TI) {
        const int ig = ig0 + tid;
        const bool iv = ig < B;
        s_t[tid] = iv ? t[ig] : 0.0f;
        s_p[tid] = iv ? p[ig] : 0.0f;
    }
    __syncthreads();

    const bool jvalid = jg < B;
    const float tjv = jvalid ? t[jg] : 0.0f;
    const float pjv = jvalid ? p[jg] : 0.0f;

    float sum  = 0.0f;
    int   cnt  = 0;
    float msev = 0.0f;

    const bool fulltile = (ig0 + TI) <= jt * TJ;

    if (jvalid) {
        if (it == 2 * jt) {          // exactly one block per j column: fold MSE
            const float d = pjv - tjv;
            msev = d * d;
        }
        if (fulltile) {
            #pragma unroll 8
            for (int ii = 0; ii < TI; ++ii) {
                const float dt = s_t[ii] - tjv;
                const float dp = s_p[ii] - pjv;
                const float sdp = (dt > 0.0f) ? dp : -dp;
                const float v = fmaxf(MARGIN - sdp, 0.0f);
                const bool valid = (dt != 0.0f);
                sum += valid ? v : 0.0f;
                cnt += valid ? 1 : 0;
            }
        } else {
            const int ilim = min(TI, B - ig0);
            const int jloc = jg - ig0;           // pair valid only if ii < jloc
            #pragma unroll 4
            for (int ii = 0; ii < ilim; ++ii) {
                const float dt = s_t[ii] - tjv;
                const float dp = s_p[ii] - pjv;
                const float sdp = (dt > 0.0f) ? dp : -dp;
                const float v = fmaxf(MARGIN - sdp, 0.0f);
                const bool valid = (dt != 0.0f) && (ii < jloc);
                sum += valid ? v : 0.0f;
                cnt += valid ? 1 : 0;
            }
        }
    }

    // 64-lane butterfly reduction
    for (int off = 32; off > 0; off >>= 1) {
        sum  += __shfl_down(sum, off);
        cnt  += __shfl_down(cnt, off);
        msev += __shfl_down(msev, off);
    }
    __shared__ float r_sum[4], r_mse[4];
    __shared__ int   r_cnt[4];
    const int wid  = tid >> 6;
    const int lane = tid & 63;
    if (lane == 0) { r_sum[wid] = sum; r_mse[wid] = msev; r_cnt[wid] = cnt; }
    __syncthreads();
    if (tid == 0) {
        bsum[bid] = r_sum[0] + r_sum[1] + r_sum[2] + r_sum[3];
        bmse[bid] = r_mse[0] + r_mse[1] + r_mse[2] + r_mse[3];
        bcnt[bid] = r_cnt[0] + r_cnt[1] + r_cnt[2] + r_cnt[3];
    }
}

// Fixed-order tree reduction over NB block partials -> deterministic.
__global__ __launch_bounds__(256) void finalize_kernel(const float* __restrict__ bsum,
                                                       const float* __restrict__ bmse,
                                                       const int*   __restrict__ bcnt,
                                                       int NB, int B,
                                                       float* __restrict__ out) {
    const int tid = threadIdx.x;
    double S = 0.0, M = 0.0;
    long long C = 0;
    for (int k = tid; k < NB; k += 256) {
        S += (double)bsum[k];
        M += (double)bmse[k];
        C += (long long)bcnt[k];
    }
    for (int off = 32; off > 0; off >>= 1) {
        S += __shfl_down(S, off);
        M += __shfl_down(M, off);
        C += __shfl_down(C, off);
    }
    __shared__ double rs[4], rm[4];
    __shared__ long long rc[4];
    const int wid  = tid >> 6;
    const int lane = tid & 63;
    if (lane == 0) { rs[wid] = S; rm[wid] = M; rc[wid] = C; }
    __syncthreads();
    if (tid == 0) {
        S = rs[0] + rs[1] + rs[2] + rs[3];
        M = rm[0] + rm[1] + rm[2] + rm[3];
        C = rc[0] + rc[1] + rc[2] + rc[3];
        const double mse  = M / (double)B;
        const double rank = (C > 0) ? (S / (double)(C > 1 ? C : 1)) : 0.0;
        out[0] = (float)((double)ALPHA * mse + (double)(1.0f - ALPHA) * rank);
    }
}

extern "C" void kernel_launch(void* const* d_in, const int* in_sizes, int n_in,
                              void* d_out, int out_size, void* d_ws, size_t ws_size,
                              hipStream_t stream) {
    const float* p = (const float*)d_in[0];
    const float* t = (const float*)d_in[1];
    const int B = in_sizes[0];

    const int NJ = (B + TJ - 1) / TJ;
    const int NB = NJ * (NJ + 1);

    float* bsum = (float*)d_ws;
    float* bmse = bsum + NB;
    int*   bcnt = (int*)(bmse + NB);

    pair_kernel<<<NB, TJ, 0, stream>>>(p, t, B, bsum, bmse, bcnt);
    finalize_kernel<<<1, 256, 0, stream>>>(bsum, bmse, bcnt, NB, B, (float*)d_out);
}